// Round 2
// baseline (1143.930 us; speedup 1.0000x reference)
//
#include <hip/hip_runtime.h>

#define B_  2
#define S_  2048
#define D_  2048
#define H_  16
#define KV_ 8
#define HD_ 128
#define SCALE_ 0.08838834764831845f

typedef __attribute__((ext_vector_type(8))) short sh8;
typedef __attribute__((ext_vector_type(4))) float f32x4;
typedef unsigned short u16;
typedef unsigned int u32;

__device__ __forceinline__ u16 f2bf(float f){
  u32 u = __float_as_uint(f);
  u += 0x7fffu + ((u >> 16) & 1u);          // RNE
  return (u16)(u >> 16);
}
__device__ __forceinline__ float bf2f(u16 h){
  return __uint_as_float(((u32)h) << 16);
}
__device__ __forceinline__ void gl_lds16(const u16* g, u16* l){
  __builtin_amdgcn_global_load_lds(
      (const __attribute__((address_space(1))) u32*)g,
      (__attribute__((address_space(3))) u32*)l, 16, 0, 0);
}

// ---------------- fp32 -> bf16 convert ----------------
__global__ void cvt_bf16(const float* __restrict__ in, u16* __restrict__ out, int n){
  int i = (blockIdx.x * blockDim.x + threadIdx.x) * 4;
  const int stride = gridDim.x * blockDim.x * 4;
  for (; i < n; i += stride){
    float4 f = *(const float4*)(in + i);
    ushort4 u;
    u.x = f2bf(f.x); u.y = f2bf(f.y); u.z = f2bf(f.z); u.w = f2bf(f.w);
    *(ushort4*)(out + i) = u;
  }
}

// ---------------- GEMM C = A @ B^T  (m97 structure: 128x128 tile, BK=32) ----------------
// MODE 0: A=x_bf16 (M=4096,K=2048), B = [wq;wk;wv] by column region, scatter to q/k/v head layouts (bf16)
// MODE 1: A=ob (M=4096,K=2048), B = wo, C = fp32 row-major d_out
template<int MODE>
__global__ __launch_bounds__(256, 2) void gemm_bt(
    const u16* __restrict__ A, const u16* __restrict__ Bq,
    const u16* __restrict__ Bk, const u16* __restrict__ Bv,
    u16* __restrict__ Oq, u16* __restrict__ Ok, u16* __restrict__ Ov,
    float* __restrict__ Of, int K)
{
  __shared__ __align__(16) u16 As[128*32];
  __shared__ __align__(16) u16 Bs[128*32];
  const int m0 = blockIdx.y * 128, n0 = blockIdx.x * 128;
  const u16* Bp; int nb;
  if (MODE == 0){
    if      (n0 < 2048){ Bp = Bq; nb = n0;        }
    else if (n0 < 3072){ Bp = Bk; nb = n0 - 2048; }
    else               { Bp = Bv; nb = n0 - 3072; }
  } else { Bp = Bq; nb = n0; }
  const int tid = threadIdx.x, lane = tid & 63, w = tid >> 6;
  const int wr = w >> 1, wc = w & 1, lg = lane >> 4, l15 = lane & 15;
  const int srow = lane >> 2, skof = (lane & 3) * 8;
  f32x4 acc[4][4];
  #pragma unroll
  for (int i = 0; i < 4; ++i)
    #pragma unroll
    for (int j = 0; j < 4; ++j) acc[i][j] = (f32x4){0.f,0.f,0.f,0.f};
  const int nkt = K >> 5;
  for (int kt = 0; kt < nkt; ++kt){
    const int k0 = kt << 5;
    __syncthreads();                 // previous iter's LDS reads done before overwrite
    #pragma unroll
    for (int c = 0; c < 2; ++c){
      const int chunk = w * 2 + c;   // wave-uniform
      gl_lds16(A  + (size_t)(m0 + chunk*16 + srow) * K + k0 + skof, As + chunk*512);
      gl_lds16(Bp + (size_t)(nb + chunk*16 + srow) * K + k0 + skof, Bs + chunk*512);
    }
    __syncthreads();                 // vmcnt(0) drain -> tiles visible
    sh8 af[4], bfr[4];
    #pragma unroll
    for (int mf = 0; mf < 4; ++mf) af[mf]  = *(const sh8*)(As + (wr*64 + mf*16 + l15)*32 + lg*8);
    #pragma unroll
    for (int nf = 0; nf < 4; ++nf) bfr[nf] = *(const sh8*)(Bs + (wc*64 + nf*16 + l15)*32 + lg*8);
    #pragma unroll
    for (int mf = 0; mf < 4; ++mf)
      #pragma unroll
      for (int nf = 0; nf < 4; ++nf)
        acc[mf][nf] = __builtin_amdgcn_mfma_f32_16x16x32_bf16(af[mf], bfr[nf], acc[mf][nf], 0, 0, 0);
  }
  // epilogue: C/D layout col=lane&15, row=(lane>>4)*4+reg  [m89-verified]
  #pragma unroll
  for (int mf = 0; mf < 4; ++mf)
    #pragma unroll
    for (int nf = 0; nf < 4; ++nf)
      #pragma unroll
      for (int r = 0; r < 4; ++r){
        const int row = m0 + wr*64 + mf*16 + lg*4 + r;
        const int col = n0 + wc*64 + nf*16 + l15;
        const float v = acc[mf][nf][r];
        if (MODE == 1){
          Of[(size_t)row * 2048 + col] = v;
        } else {
          const int b = row >> 11, s = row & 2047;
          const u16 u = f2bf(v);
          if (col < 2048){
            const int h = col >> 7, d = col & 127;
            Oq[((size_t)(b*H_ + h)*S_ + s)*HD_ + d] = u;
          } else if (col < 3072){
            const int kv = (col - 2048) >> 7, d = col & 127;
            Ok[((size_t)(b*KV_ + kv)*S_ + s)*HD_ + d] = u;
          } else {
            const int kv = (col - 3072) >> 7, d = col & 127;
            Ov[((size_t)(b*KV_ + kv)*S_ + s)*HD_ + d] = u;
          }
        }
      }
}

// ---------------- fused RMSNorm + RoPE (in-place on bf16 head-major rows) ----------------
// one wave per (b, head, s) row of 128; lane l owns pair (l, l+64) -> rotate_half is local
__global__ __launch_bounds__(256) void rmsrope(
    u16* __restrict__ qk, const float* __restrict__ cosb, const float* __restrict__ sinb,
    const float* __restrict__ wn, int nh)
{
  const int lane = threadIdx.x & 63;
  const int row  = blockIdx.x * 4 + (threadIdx.x >> 6);   // (b*nh + h)*S + s
  const int s    = row & (S_ - 1);
  const int b    = (row >> 11) / nh;
  u16* p = qk + (size_t)row * HD_;
  float x0 = bf2f(p[lane]), x1 = bf2f(p[lane + 64]);
  float ss = x0*x0 + x1*x1;
  #pragma unroll
  for (int mm = 1; mm < 64; mm <<= 1) ss += __shfl_xor(ss, mm, 64);
  const float rs = rsqrtf(ss * (1.0f/128.0f) + 1e-6f);
  const float n0 = x0 * rs * wn[lane], n1 = x1 * rs * wn[lane + 64];
  const float* cp = cosb + ((size_t)b*S_ + s)*HD_;
  const float* sp = sinb + ((size_t)b*S_ + s)*HD_;
  const float o0 = n0 * cp[lane]      - n1 * sp[lane];
  const float o1 = n1 * cp[lane + 64] + n0 * sp[lane + 64];
  p[lane] = f2bf(o0); p[lane + 64] = f2bf(o1);
}

// ---------------- attention pass A: per-row online max / sumexp ----------------
__global__ __launch_bounds__(256, 2) void attn_stats(
    const u16* __restrict__ Q, const u16* __restrict__ Kc,
    float* __restrict__ mrow, float* __restrict__ lrow)
{
  __shared__ __align__(16) u16 Ks[64*136];       // padded: stride 136 -> 2-way only
  const int qblk = blockIdx.x, bh = blockIdx.y;
  const int b = bh >> 4, h = bh & 15, kv = h >> 1;
  const u16* Qp = Q + ((size_t)(b*H_ + h)*S_ + qblk*64)*HD_;
  const u16* Kp = Kc + (size_t)(b*KV_ + kv)*S_*HD_;
  const int tid = threadIdx.x, lane = tid & 63, w = tid >> 6;
  const int lg = lane >> 4, l15 = lane & 15;
  sh8 aq[4];
  #pragma unroll
  for (int kk = 0; kk < 4; ++kk)
    aq[kk] = *(const sh8*)(Qp + (w*16 + l15)*HD_ + kk*32 + lg*8);
  float m_i[4] = {-1e30f,-1e30f,-1e30f,-1e30f};
  float l_i[4] = {0.f,0.f,0.f,0.f};
  const int row0 = qblk*64 + w*16 + lg*4;
  for (int jb = 0; jb <= qblk; ++jb){
    #pragma unroll
    for (int i = 0; i < 4; ++i){
      const int flat = tid + i*256;
      const int r = flat >> 4, kof = (flat & 15) * 8;
      *(sh8*)(Ks + r*136 + kof) = *(const sh8*)(Kp + (size_t)(jb*64 + r)*HD_ + kof);
    }
    __syncthreads();
    f32x4 sacc[4];
    #pragma unroll
    for (int nf = 0; nf < 4; ++nf) sacc[nf] = (f32x4){0.f,0.f,0.f,0.f};
    #pragma unroll
    for (int kk = 0; kk < 4; ++kk)
      #pragma unroll
      for (int nf = 0; nf < 4; ++nf){
        sh8 bk = *(const sh8*)(Ks + (nf*16 + l15)*136 + kk*32 + lg*8);
        sacc[nf] = __builtin_amdgcn_mfma_f32_16x16x32_bf16(aq[kk], bk, sacc[nf], 0, 0, 0);
      }
    __syncthreads();                 // reads done -> safe to restage next iter
    const bool diag = (jb == qblk);
    #pragma unroll
    for (int r = 0; r < 4; ++r){
      float sc[4]; float mx = -1e30f;
      #pragma unroll
      for (int nf = 0; nf < 4; ++nf){
        float v = sacc[nf][r] * SCALE_;
        if (diag && (jb*64 + nf*16 + l15) > (row0 + r)) v = -1e9f;
        sc[nf] = v; mx = fmaxf(mx, v);
      }
      #pragma unroll
      for (int mm = 1; mm < 16; mm <<= 1) mx = fmaxf(mx, __shfl_xor(mx, mm, 64));
      const float mnew = fmaxf(m_i[r], mx);
      float ps = __expf(sc[0]-mnew) + __expf(sc[1]-mnew) + __expf(sc[2]-mnew) + __expf(sc[3]-mnew);
      #pragma unroll
      for (int mm = 1; mm < 16; mm <<= 1) ps += __shfl_xor(ps, mm, 64);
      l_i[r] = l_i[r]*__expf(m_i[r]-mnew) + ps;
      m_i[r] = mnew;
    }
  }
  if (l15 == 0){
    #pragma unroll
    for (int r = 0; r < 4; ++r){
      const size_t gr = (size_t)(b*H_ + h)*S_ + row0 + r;
      mrow[gr] = m_i[r]; lrow[gr] = l_i[r];
    }
  }
}

// ---------------- attention pass B: recompute scores, write probs fp32, fused PV ----------------
__global__ __launch_bounds__(256, 2) void attn_pv(
    const u16* __restrict__ Q, const u16* __restrict__ Kc, const u16* __restrict__ V,
    const float* __restrict__ mrow, const float* __restrict__ lrow,
    float* __restrict__ attn, u16* __restrict__ Ob)
{
  __shared__ __align__(16) u16 Ks[64*136];
  __shared__ __align__(16) u16 Vt[128*72];   // V transposed: Vt[d][j]
  __shared__ __align__(16) u16 Ps[64*72];    // P tile for MFMA A-frags
  const int qblk = blockIdx.x, bh = blockIdx.y;
  const int b = bh >> 4, h = bh & 15, kv = h >> 1;
  const u16* Qp = Q + ((size_t)(b*H_ + h)*S_ + qblk*64)*HD_;
  const u16* Kp = Kc + (size_t)(b*KV_ + kv)*S_*HD_;
  const u16* Vp = V  + (size_t)(b*KV_ + kv)*S_*HD_;
  const int tid = threadIdx.x, lane = tid & 63, w = tid >> 6;
  const int lg = lane >> 4, l15 = lane & 15;
  sh8 aq[4];
  #pragma unroll
  for (int kk = 0; kk < 4; ++kk)
    aq[kk] = *(const sh8*)(Qp + (w*16 + l15)*HD_ + kk*32 + lg*8);
  const int row0 = qblk*64 + w*16 + lg*4;
  float m4[4], linv[4];
  #pragma unroll
  for (int r = 0; r < 4; ++r){
    const size_t gr = (size_t)(b*H_ + h)*S_ + row0 + r;
    m4[r] = mrow[gr]; linv[r] = 1.0f / lrow[gr];
  }
  f32x4 o[8];
  #pragma unroll
  for (int i = 0; i < 8; ++i) o[i] = (f32x4){0.f,0.f,0.f,0.f};
  float* ab = attn + ((size_t)(b*H_ + h)*S_ + qblk*64)*S_;
  for (int jb = 0; jb <= qblk; ++jb){
    #pragma unroll
    for (int i = 0; i < 4; ++i){
      const int flat = tid + i*256;
      const int r = flat >> 4, kof = (flat & 15) * 8;
      *(sh8*)(Ks + r*136 + kof) = *(const sh8*)(Kp + (size_t)(jb*64 + r)*HD_ + kof);
      sh8 vv = *(const sh8*)(Vp + (size_t)(jb*64 + r)*HD_ + kof);
      #pragma unroll
      for (int e = 0; e < 8; ++e) Vt[(kof + e)*72 + r] = (u16)vv[e];
    }
    __syncthreads();
    f32x4 sacc[4];
    #pragma unroll
    for (int nf = 0; nf < 4; ++nf) sacc[nf] = (f32x4){0.f,0.f,0.f,0.f};
    #pragma unroll
    for (int kk = 0; kk < 4; ++kk)
      #pragma unroll
      for (int nf = 0; nf < 4; ++nf){
        sh8 bk = *(const sh8*)(Ks + (nf*16 + l15)*136 + kk*32 + lg*8);
        sacc[nf] = __builtin_amdgcn_mfma_f32_16x16x32_bf16(aq[kk], bk, sacc[nf], 0, 0, 0);
      }
    const bool diag = (jb == qblk);
    #pragma unroll
    for (int r = 0; r < 4; ++r)
      #pragma unroll
      for (int nf = 0; nf < 4; ++nf){
        const int col = jb*64 + nf*16 + l15;
        float v = sacc[nf][r] * SCALE_;
        if (diag && col > row0 + r) v = -1e9f;
        const float pn = __expf(v - m4[r]) * linv[r];   // exact 0 above diagonal
        ab[(size_t)(w*16 + lg*4 + r)*S_ + col] = pn;
        Ps[(w*16 + lg*4 + r)*72 + nf*16 + l15] = f2bf(pn);
      }
    // PV: wave-local Ps rows (no cross-wave barrier needed before reads)
    #pragma unroll
    for (int kk = 0; kk < 2; ++kk){
      sh8 pa = *(const sh8*)(Ps + (w*16 + l15)*72 + kk*32 + lg*8);
      #pragma unroll
      for (int nf2 = 0; nf2 < 8; ++nf2){
        sh8 bv = *(const sh8*)(Vt + (nf2*16 + l15)*72 + kk*32 + lg*8);
        o[nf2] = __builtin_amdgcn_mfma_f32_16x16x32_bf16(pa, bv, o[nf2], 0, 0, 0);
      }
    }
    __syncthreads();                 // Ks/Vt reads done -> safe to restage
  }
  // zero-fill strictly-upper column blocks of the probs output
  {
    const int c0 = (qblk + 1) * 64;
    const int nq = S_ - c0;
    if (nq > 0){
      const int quads = nq >> 2;
      const int total = 64 * quads;
      for (int idx = tid; idx < total; idx += 256){
        const int rr = idx / quads, cc = (idx % quads) * 4;
        *(float4*)(ab + (size_t)rr * S_ + c0 + cc) = make_float4(0.f,0.f,0.f,0.f);
      }
    }
  }
  // write O in (b, s, h, d) bf16 layout for the out-projection GEMM
  #pragma unroll
  for (int nf2 = 0; nf2 < 8; ++nf2)
    #pragma unroll
    for (int r = 0; r < 4; ++r){
      const int sg = qblk*64 + w*16 + lg*4 + r;
      Ob[((size_t)(b*S_ + sg)*H_ + h)*HD_ + nf2*16 + l15] = f2bf(o[nf2][r]);
    }
}

// ---------------- launcher ----------------
extern "C" void kernel_launch(void* const* d_in, const int* in_sizes, int n_in,
                              void* d_out, int out_size, void* d_ws, size_t ws_size,
                              hipStream_t stream)
{
  const float* x    = (const float*)d_in[0];
  const float* cosp = (const float*)d_in[1];
  const float* sinp = (const float*)d_in[2];
  // d_in[3] = attention_mask: causal, applied analytically
  const float* wq   = (const float*)d_in[4];
  const float* wk   = (const float*)d_in[5];
  const float* wv   = (const float*)d_in[6];
  const float* wo   = (const float*)d_in[7];
  const float* qnw  = (const float*)d_in[8];
  const float* knw  = (const float*)d_in[9];

  const size_t N_X  = (size_t)B_*S_*D_;        // 8388608
  const size_t N_WQ = (size_t)H_*HD_*D_;       // 4194304
  const size_t N_WK = (size_t)KV_*HD_*D_;      // 2097152
  const size_t N_WO = (size_t)D_*H_*HD_;       // 4194304
  const size_t N_Q  = (size_t)B_*H_*S_*HD_;    // 8388608
  const size_t N_K  = (size_t)B_*KV_*S_*HD_;   // 4194304

  u16* xb  = (u16*)d_ws;
  u16* wqb = xb  + N_X;
  u16* wkb = wqb + N_WQ;
  u16* wvb = wkb + N_WK;
  u16* wob = wvb + N_WK;
  u16* qb  = wob + N_WO;
  u16* kb  = qb  + N_Q;
  u16* vb  = kb  + N_K;
  u16* ob  = vb  + N_K;
  float* mrow = (float*)(ob + N_X);
  float* lrow = mrow + (size_t)B_*H_*S_;

  float* out0 = (float*)d_out;                 // attn_output (B,S,2048)
  float* attn = out0 + N_X;                    // attn probs (B,H,S,S)

  cvt_bf16<<<1024, 256, 0, stream>>>(x,  xb,  (int)N_X);
  cvt_bf16<<<512,  256, 0, stream>>>(wq, wqb, (int)N_WQ);
  cvt_bf16<<<256,  256, 0, stream>>>(wk, wkb, (int)N_WK);
  cvt_bf16<<<256,  256, 0, stream>>>(wv, wvb, (int)N_WK);
  cvt_bf16<<<512,  256, 0, stream>>>(wo, wob, (int)N_WO);

  gemm_bt<0><<<dim3(32, 32), 256, 0, stream>>>(xb, wqb, wkb, wvb, qb, kb, vb, nullptr, 2048);

  rmsrope<<<(B_*H_*S_)/4,  256, 0, stream>>>(qb, cosp, sinp, qnw, H_);
  rmsrope<<<(B_*KV_*S_)/4, 256, 0, stream>>>(kb, cosp, sinp, knw, KV_);

  attn_stats<<<dim3(S_/64, B_*H_), 256, 0, stream>>>(qb, kb, mrow, lrow);
  attn_pv  <<<dim3(S_/64, B_*H_), 256, 0, stream>>>(qb, kb, vb, mrow, lrow, attn, ob);

  gemm_bt<1><<<dim3(16, 32), 256, 0, stream>>>(ob, wob, nullptr, nullptr,
                                               nullptr, nullptr, nullptr, out0, 2048);
}

// Round 3
// 1059.037 us; speedup vs baseline: 1.0802x; 1.0802x over previous
//
#include <hip/hip_runtime.h>

#define B_  2
#define S_  2048
#define D_  2048
#define H_  16
#define KV_ 8
#define HD_ 128
#define SCALE_ 0.08838834764831845f

typedef __attribute__((ext_vector_type(8))) short sh8;
typedef __attribute__((ext_vector_type(4))) float f32x4;
typedef unsigned short u16;
typedef unsigned int u32;

__device__ __forceinline__ u16 f2bf(float f){
  u32 u = __float_as_uint(f);
  u += 0x7fffu + ((u >> 16) & 1u);          // RNE
  return (u16)(u >> 16);
}
__device__ __forceinline__ float bf2f(u16 h){
  return __uint_as_float(((u32)h) << 16);
}
__device__ __forceinline__ void gl_lds16(const u16* g, u16* l){
  __builtin_amdgcn_global_load_lds(
      (const __attribute__((address_space(1))) u32*)g,
      (__attribute__((address_space(3))) u32*)l, 16, 0, 0);
}

// ---------------- fp32 -> bf16 convert ----------------
__global__ void cvt_bf16(const float* __restrict__ in, u16* __restrict__ out, int n){
  int i = (blockIdx.x * blockDim.x + threadIdx.x) * 4;
  const int stride = gridDim.x * blockDim.x * 4;
  for (; i < n; i += stride){
    float4 f = *(const float4*)(in + i);
    ushort4 u;
    u.x = f2bf(f.x); u.y = f2bf(f.y); u.z = f2bf(f.z); u.w = f2bf(f.w);
    *(ushort4*)(out + i) = u;
  }
}

// ---------------- GEMM C = A @ B^T  (m97 structure: 128x128 tile, BK=32) ----------------
template<int MODE>
__global__ __launch_bounds__(256, 2) void gemm_bt(
    const u16* __restrict__ A, const u16* __restrict__ Bq,
    const u16* __restrict__ Bk, const u16* __restrict__ Bv,
    u16* __restrict__ Oq, u16* __restrict__ Ok, u16* __restrict__ Ov,
    float* __restrict__ Of, int K)
{
  __shared__ __align__(16) u16 As[128*32];
  __shared__ __align__(16) u16 Bs[128*32];
  const int m0 = blockIdx.y * 128, n0 = blockIdx.x * 128;
  const u16* Bp; int nb;
  if (MODE == 0){
    if      (n0 < 2048){ Bp = Bq; nb = n0;        }
    else if (n0 < 3072){ Bp = Bk; nb = n0 - 2048; }
    else               { Bp = Bv; nb = n0 - 3072; }
  } else { Bp = Bq; nb = n0; }
  const int tid = threadIdx.x, lane = tid & 63, w = tid >> 6;
  const int wr = w >> 1, wc = w & 1, lg = lane >> 4, l15 = lane & 15;
  const int srow = lane >> 2, skof = (lane & 3) * 8;
  f32x4 acc[4][4];
  #pragma unroll
  for (int i = 0; i < 4; ++i)
    #pragma unroll
    for (int j = 0; j < 4; ++j) acc[i][j] = (f32x4){0.f,0.f,0.f,0.f};
  const int nkt = K >> 5;
  for (int kt = 0; kt < nkt; ++kt){
    const int k0 = kt << 5;
    __syncthreads();
    #pragma unroll
    for (int c = 0; c < 2; ++c){
      const int chunk = w * 2 + c;   // wave-uniform
      gl_lds16(A  + (size_t)(m0 + chunk*16 + srow) * K + k0 + skof, As + chunk*512);
      gl_lds16(Bp + (size_t)(nb + chunk*16 + srow) * K + k0 + skof, Bs + chunk*512);
    }
    __syncthreads();
    sh8 af[4], bfr[4];
    #pragma unroll
    for (int mf = 0; mf < 4; ++mf) af[mf]  = *(const sh8*)(As + (wr*64 + mf*16 + l15)*32 + lg*8);
    #pragma unroll
    for (int nf = 0; nf < 4; ++nf) bfr[nf] = *(const sh8*)(Bs + (wc*64 + nf*16 + l15)*32 + lg*8);
    #pragma unroll
    for (int mf = 0; mf < 4; ++mf)
      #pragma unroll
      for (int nf = 0; nf < 4; ++nf)
        acc[mf][nf] = __builtin_amdgcn_mfma_f32_16x16x32_bf16(af[mf], bfr[nf], acc[mf][nf], 0, 0, 0);
  }
  #pragma unroll
  for (int mf = 0; mf < 4; ++mf)
    #pragma unroll
    for (int nf = 0; nf < 4; ++nf)
      #pragma unroll
      for (int r = 0; r < 4; ++r){
        const int row = m0 + wr*64 + mf*16 + lg*4 + r;
        const int col = n0 + wc*64 + nf*16 + l15;
        const float v = acc[mf][nf][r];
        if (MODE == 1){
          Of[(size_t)row * 2048 + col] = v;
        } else {
          const int b = row >> 11, s = row & 2047;
          const u16 u = f2bf(v);
          if (col < 2048){
            const int h = col >> 7, d = col & 127;
            Oq[((size_t)(b*H_ + h)*S_ + s)*HD_ + d] = u;
          } else if (col < 3072){
            const int kv = (col - 2048) >> 7, d = col & 127;
            Ok[((size_t)(b*KV_ + kv)*S_ + s)*HD_ + d] = u;
          } else {
            const int kv = (col - 3072) >> 7, d = col & 127;
            Ov[((size_t)(b*KV_ + kv)*S_ + s)*HD_ + d] = u;
          }
        }
      }
}

// ---------------- fused RMSNorm + RoPE ----------------
__global__ __launch_bounds__(256) void rmsrope(
    u16* __restrict__ qk, const float* __restrict__ cosb, const float* __restrict__ sinb,
    const float* __restrict__ wn, int nh)
{
  const int lane = threadIdx.x & 63;
  const int row  = blockIdx.x * 4 + (threadIdx.x >> 6);   // (b*nh + h)*S + s
  const int s    = row & (S_ - 1);
  const int b    = (row >> 11) / nh;
  u16* p = qk + (size_t)row * HD_;
  float x0 = bf2f(p[lane]), x1 = bf2f(p[lane + 64]);
  float ss = x0*x0 + x1*x1;
  #pragma unroll
  for (int mm = 1; mm < 64; mm <<= 1) ss += __shfl_xor(ss, mm, 64);
  const float rs = rsqrtf(ss * (1.0f/128.0f) + 1e-6f);
  const float n0 = x0 * rs * wn[lane], n1 = x1 * rs * wn[lane + 64];
  const float* cp = cosb + ((size_t)b*S_ + s)*HD_;
  const float* sp = sinb + ((size_t)b*S_ + s)*HD_;
  const float o0 = n0 * cp[lane]      - n1 * sp[lane];
  const float o1 = n1 * cp[lane + 64] + n0 * sp[lane + 64];
  p[lane] = f2bf(o0); p[lane + 64] = f2bf(o1);
}

// ---------------- single-pass attention: no-max softmax, unnormalized P ----------------
// QBLK=128 rows/block, KVBLK=64. Writes bf16 unnormalized P to scratch Pb,
// accumulates unnormalized O (bf16 to Ob). Normalization deferred.
__global__ __launch_bounds__(256, 2) void attn_fused(
    const u16* __restrict__ Q, const u16* __restrict__ Kc, const u16* __restrict__ V,
    u16* __restrict__ Pb, u16* __restrict__ Ob)
{
  __shared__ __align__(16) u16 Ks[64*136];
  __shared__ __align__(16) u16 Vt[128*72];   // V transposed: Vt[d][j]
  __shared__ __align__(16) u16 Ps[128*72];   // bf16 P tile
  const int qblk = (S_/128 - 1) - blockIdx.x;   // longest blocks first
  const int bh = blockIdx.y;
  const int b = bh >> 4, h = bh & 15, kv = h >> 1;
  const u16* Qp = Q  + ((size_t)(b*H_ + h)*S_ + qblk*128)*HD_;
  const u16* Kp = Kc + (size_t)(b*KV_ + kv)*S_*HD_;
  const u16* Vp = V  + (size_t)(b*KV_ + kv)*S_*HD_;
  u16* Pq = Pb + ((size_t)(b*H_ + h)*S_ + qblk*128)*S_;
  const int tid = threadIdx.x, lane = tid & 63, w = tid >> 6;
  const int lg = lane >> 4, l15 = lane & 15;
  sh8 aq[2][4];
  #pragma unroll
  for (int mf = 0; mf < 2; ++mf)
    #pragma unroll
    for (int kk = 0; kk < 4; ++kk)
      aq[mf][kk] = *(const sh8*)(Qp + (w*32 + mf*16 + l15)*HD_ + kk*32 + lg*8);
  f32x4 o[2][8];
  #pragma unroll
  for (int mf = 0; mf < 2; ++mf)
    #pragma unroll
    for (int i = 0; i < 8; ++i) o[mf][i] = (f32x4){0.f,0.f,0.f,0.f};
  const int jbmax = 2*qblk + 1;
  for (int jb = 0; jb <= jbmax; ++jb){
    __syncthreads();                 // prior iter's LDS reads complete
    #pragma unroll
    for (int i = 0; i < 4; ++i){
      const int flat = tid + i*256;
      const int r = flat >> 4, kof = (flat & 15) * 8;
      *(sh8*)(Ks + r*136 + kof) = *(const sh8*)(Kp + (size_t)(jb*64 + r)*HD_ + kof);
      sh8 vv = *(const sh8*)(Vp + (size_t)(jb*64 + r)*HD_ + kof);
      #pragma unroll
      for (int e = 0; e < 8; ++e) Vt[(kof + e)*72 + r] = (u16)vv[e];
    }
    __syncthreads();
    // QK^T
    f32x4 sacc[2][4];
    #pragma unroll
    for (int mf = 0; mf < 2; ++mf)
      #pragma unroll
      for (int nf = 0; nf < 4; ++nf) sacc[mf][nf] = (f32x4){0.f,0.f,0.f,0.f};
    #pragma unroll
    for (int kk = 0; kk < 4; ++kk)
      #pragma unroll
      for (int nf = 0; nf < 4; ++nf){
        sh8 bk = *(const sh8*)(Ks + (nf*16 + l15)*136 + kk*32 + lg*8);
        #pragma unroll
        for (int mf = 0; mf < 2; ++mf)
          sacc[mf][nf] = __builtin_amdgcn_mfma_f32_16x16x32_bf16(aq[mf][kk], bk, sacc[mf][nf], 0, 0, 0);
      }
    // exp (no max needed: |s*scale| <= 11.32 by RMSNorm bound) -> Ps
    const bool dblk = (jb >= 2*qblk);
    #pragma unroll
    for (int mf = 0; mf < 2; ++mf)
      #pragma unroll
      for (int nf = 0; nf < 4; ++nf)
        #pragma unroll
        for (int r = 0; r < 4; ++r){
          const int row = qblk*128 + w*32 + mf*16 + lg*4 + r;
          const int col = jb*64 + nf*16 + l15;
          float p = __expf(sacc[mf][nf][r] * SCALE_);
          if (dblk && col > row) p = 0.f;
          Ps[(w*32 + mf*16 + lg*4 + r)*72 + nf*16 + l15] = f2bf(p);
        }
    // PV (wave-local Ps rows; per-wave DS ordering makes this safe)
    #pragma unroll
    for (int mf = 0; mf < 2; ++mf)
      #pragma unroll
      for (int kk = 0; kk < 2; ++kk){
        sh8 pa = *(const sh8*)(Ps + (w*32 + mf*16 + l15)*72 + kk*32 + lg*8);
        #pragma unroll
        for (int nf2 = 0; nf2 < 8; ++nf2){
          sh8 bv = *(const sh8*)(Vt + (nf2*16 + l15)*72 + kk*32 + lg*8);
          o[mf][nf2] = __builtin_amdgcn_mfma_f32_16x16x32_bf16(pa, bv, o[mf][nf2], 0, 0, 0);
        }
      }
    __syncthreads();                 // all waves' Ps rows visible
    // coalesced copy-out Ps -> Pb (16B stores)
    #pragma unroll
    for (int i = 0; i < 4; ++i){
      const int id = tid + i*256;
      const int row = id >> 3, cc = (id & 7) * 8;
      *(sh8*)(Pq + (size_t)row*S_ + jb*64 + cc) = *(const sh8*)(Ps + row*72 + cc);
    }
  }
  // write unnormalized O (b, s, h, d) bf16
  #pragma unroll
  for (int mf = 0; mf < 2; ++mf)
    #pragma unroll
    for (int nf2 = 0; nf2 < 8; ++nf2)
      #pragma unroll
      for (int r = 0; r < 4; ++r){
        const int sg = qblk*128 + w*32 + mf*16 + lg*4 + r;
        Ob[((size_t)(b*S_ + sg)*H_ + h)*HD_ + nf2*16 + l15] = f2bf(o[mf][nf2][r]);
      }
}

// ---------------- normalize probs: one wave per row; computes l, writes fp32 + zeros ----------------
__global__ __launch_bounds__(256) void prob_norm(
    const u16* __restrict__ Pb, float* __restrict__ attn, float* __restrict__ invl)
{
  const int w = threadIdx.x >> 6, lane = threadIdx.x & 63;
  const int row = blockIdx.x * 4 + w;         // (b*H + h)*S + q
  const int q = row & (S_ - 1);
  const int nread = ((q >> 7) + 1) * 128;     // cols written by attn_fused
  const u16* pr = Pb + (size_t)row * S_;
  float* ar = attn + (size_t)row * S_;
  float pv[4][8];
  float sum = 0.f;
  #pragma unroll
  for (int c = 0; c < 4; ++c){
    const int col0 = c*512 + lane*8;
    if (col0 < nread){
      sh8 v = *(const sh8*)(pr + col0);
      #pragma unroll
      for (int e = 0; e < 8; ++e){ pv[c][e] = bf2f((u16)v[e]); sum += pv[c][e]; }
    } else {
      #pragma unroll
      for (int e = 0; e < 8; ++e) pv[c][e] = 0.f;
    }
  }
  #pragma unroll
  for (int mm = 1; mm < 64; mm <<= 1) sum += __shfl_xor(sum, mm, 64);
  const float inv = 1.0f / sum;
  if (lane == 0) invl[row] = inv;
  #pragma unroll
  for (int c = 0; c < 4; ++c){
    const int col0 = c*512 + lane*8;
    float4 f0 = make_float4(pv[c][0]*inv, pv[c][1]*inv, pv[c][2]*inv, pv[c][3]*inv);
    float4 f1 = make_float4(pv[c][4]*inv, pv[c][5]*inv, pv[c][6]*inv, pv[c][7]*inv);
    *(float4*)(ar + col0)     = f0;
    *(float4*)(ar + col0 + 4) = f1;
  }
}

// ---------------- rescale O by 1/l (in place, bf16) ----------------
__global__ __launch_bounds__(256) void o_norm(u16* __restrict__ Ob, const float* __restrict__ invl){
  const int idx = blockIdx.x * 256 + threadIdx.x;   // chunk of 8
  const int rob = idx >> 4, d0 = (idx & 15) * 8;    // rob = (b*S+s)*H+h
  const int h = rob & 15, s = (rob >> 4) & (S_-1), b = rob >> 15;
  const float inv = invl[((size_t)(b*H_ + h))*S_ + s];
  u16* p = Ob + (size_t)rob * HD_ + d0;
  sh8 v = *(const sh8*)p;
  #pragma unroll
  for (int e = 0; e < 8; ++e) v[e] = (short)f2bf(bf2f((u16)v[e]) * inv);
  *(sh8*)p = v;
}

// ---------------- launcher ----------------
extern "C" void kernel_launch(void* const* d_in, const int* in_sizes, int n_in,
                              void* d_out, int out_size, void* d_ws, size_t ws_size,
                              hipStream_t stream)
{
  const float* x    = (const float*)d_in[0];
  const float* cosp = (const float*)d_in[1];
  const float* sinp = (const float*)d_in[2];
  // d_in[3] = attention_mask: causal, applied analytically
  const float* wq   = (const float*)d_in[4];
  const float* wk   = (const float*)d_in[5];
  const float* wv   = (const float*)d_in[6];
  const float* wo   = (const float*)d_in[7];
  const float* qnw  = (const float*)d_in[8];
  const float* knw  = (const float*)d_in[9];

  const size_t N_X  = (size_t)B_*S_*D_;        // 8388608
  const size_t N_WQ = (size_t)H_*HD_*D_;       // 4194304
  const size_t N_WK = (size_t)KV_*HD_*D_;      // 2097152
  const size_t N_WO = (size_t)D_*H_*HD_;       // 4194304
  const size_t N_Q  = (size_t)B_*H_*S_*HD_;    // 8388608
  const size_t N_K  = (size_t)B_*KV_*S_*HD_;   // 4194304
  const size_t N_P  = (size_t)B_*H_*S_*S_;     // 134217728

  u16* xb  = (u16*)d_ws;
  u16* wqb = xb  + N_X;
  u16* wkb = wqb + N_WQ;
  u16* wvb = wkb + N_WK;
  u16* wob = wvb + N_WK;
  u16* qb  = wob + N_WO;
  u16* kb  = qb  + N_Q;
  u16* vb  = kb  + N_K;
  u16* ob  = vb  + N_K;
  u16* Pb  = ob  + N_X;
  float* invl = (float*)(Pb + N_P);            // B*H*S floats

  float* out0 = (float*)d_out;                 // attn_output (B,S,2048)
  float* attn = out0 + N_X;                    // attn probs (B,H,S,S)

  cvt_bf16<<<1024, 256, 0, stream>>>(x,  xb,  (int)N_X);
  cvt_bf16<<<512,  256, 0, stream>>>(wq, wqb, (int)N_WQ);
  cvt_bf16<<<256,  256, 0, stream>>>(wk, wkb, (int)N_WK);
  cvt_bf16<<<256,  256, 0, stream>>>(wv, wvb, (int)N_WK);
  cvt_bf16<<<512,  256, 0, stream>>>(wo, wob, (int)N_WO);

  gemm_bt<0><<<dim3(32, 32), 256, 0, stream>>>(xb, wqb, wkb, wvb, qb, kb, vb, nullptr, 2048);

  rmsrope<<<(B_*H_*S_)/4,  256, 0, stream>>>(qb, cosp, sinp, qnw, H_);
  rmsrope<<<(B_*KV_*S_)/4, 256, 0, stream>>>(kb, cosp, sinp, knw, KV_);

  attn_fused<<<dim3(S_/128, B_*H_), 256, 0, stream>>>(qb, kb, vb, Pb, ob);
  prob_norm <<<(B_*H_*S_)/4, 256, 0, stream>>>(Pb, attn, invl);
  o_norm    <<<(B_*S_*H_*HD_/8)/256, 256, 0, stream>>>(ob, invl);

  gemm_bt<1><<<dim3(16, 32), 256, 0, stream>>>(ob, wob, nullptr, nullptr,
                                               nullptr, nullptr, nullptr, out0, 2048);
}